// Round 3
// baseline (680.612 us; speedup 1.0000x reference)
//
#include <hip/hip_runtime.h>
#include <hip/hip_bf16.h>
#include <math.h>

// Segment-prefix max over [2048 segs x 512 rows x 128 fp32]; per segment,
// max over first (size - window + 1) rows. Memory-bound: ~535 MB read,
// roofline ~85-110 us @ 6.3 TB/s. R1/R2 showed dur_us (~672) includes
// ~500 us of harness reset traffic; kernel itself is <332 us (absent from
// top-5). R3: (1) move the O(seg)-per-block prefix-sum preamble into a tiny
// scan pre-kernel, (2) unroll 8 for more outstanding VMEM, (3) split each
// segment across 2 blocks + trivial combine, to fill block-retire bubbles.

#define BLOCK  256
#define SLICES 2

__device__ __forceinline__ float4 fmax4(float4 a, float4 b) {
    return make_float4(fmaxf(a.x, b.x), fmaxf(a.y, b.y),
                       fmaxf(a.z, b.z), fmaxf(a.w, b.w));
}

// ---- kernel 0: exclusive scan of sizes -> starts (single block) ----
__global__ __launch_bounds__(BLOCK)
void scan_kernel(const int* __restrict__ sizes, int* __restrict__ starts,
                 int n_seg) {
    __shared__ int sums[BLOCK];
    const int tid = threadIdx.x;
    const int per = (n_seg + BLOCK - 1) / BLOCK;
    const int lo  = tid * per;
    const int hi  = min(lo + per, n_seg);
    int s = 0;
    for (int i = lo; i < hi; ++i) s += sizes[i];
    sums[tid] = s;
    __syncthreads();
    // Hillis-Steele inclusive scan over the 256 per-thread sums
    for (int off = 1; off < BLOCK; off <<= 1) {
        int v = (tid >= off) ? sums[tid - off] : 0;
        __syncthreads();
        if (tid >= off) sums[tid] += v;
        __syncthreads();
    }
    int base = (tid == 0) ? 0 : sums[tid - 1];
    for (int i = lo; i < hi; ++i) {
        starts[i] = base;
        base += sizes[i];
    }
}

// ---- kernel 1: sliced segment max -> partials ----
__global__ __launch_bounds__(BLOCK)
void seg_max_kernel(const float* __restrict__ x,
                    const int* __restrict__ sizes,
                    const int* __restrict__ starts,
                    const int* __restrict__ wptr,
                    float* __restrict__ partials,
                    int nc4) {
    const int b     = blockIdx.x;
    const int seg   = b / SLICES;
    const int slice = b % SLICES;
    const int tid   = threadIdx.x;

    const int L     = sizes[seg] - *wptr + 1;       // valid rows (510 here)
    const long long start = starts[seg];
    const int lo = (int)(((long long)slice * L) / SLICES);
    const int hi = (int)(((long long)(slice + 1) * L) / SLICES);
    const int n  = hi - lo;                          // rows for this slice

    const int col4 = tid & 31;                       // 32 float4 = 128 dims
    const int rg   = tid >> 5;                       // 8 row groups

    float4 acc = make_float4(-INFINITY, -INFINITY, -INFINITY, -INFINITY);

    if (col4 < nc4) {
        const float4* xb = (const float4*)x + (size_t)(start + lo) * nc4 + col4;
        #pragma unroll 8
        for (int r = rg; r < n; r += 8)
            acc = fmax4(acc, xb[(size_t)r * nc4]);
    }

    __shared__ float4 part[8][32];
    if (col4 < nc4) part[rg][col4] = acc;
    __syncthreads();

    if (tid < nc4) {
        float4 a = part[0][tid];
        #pragma unroll
        for (int j = 1; j < 8; ++j) a = fmax4(a, part[j][tid]);
        ((float4*)partials)[((size_t)seg * SLICES + slice) * nc4 + tid] = a;
    }
}

// ---- kernel 2: combine slice partials -> out ----
__global__ __launch_bounds__(BLOCK)
void combine_kernel(const float* __restrict__ partials,
                    float* __restrict__ out,
                    int total4, int nc4) {
    const int i = blockIdx.x * BLOCK + threadIdx.x;  // one float4 of out
    if (i >= total4) return;
    const int seg = i / nc4;
    const int c   = i - seg * nc4;
    const float4* p = (const float4*)partials + (size_t)seg * SLICES * nc4 + c;
    float4 a = p[0];
    #pragma unroll
    for (int j = 1; j < SLICES; ++j) a = fmax4(a, p[(size_t)j * nc4]);
    ((float4*)out)[i] = a;
}

extern "C" void kernel_launch(void* const* d_in, const int* in_sizes, int n_in,
                              void* d_out, int out_size, void* d_ws, size_t ws_size,
                              hipStream_t stream) {
    const float* x     = (const float*)d_in[0];
    const int*   sizes = (const int*)d_in[1];
    const int*   wptr  = (const int*)d_in[2];
    float*       out   = (float*)d_out;

    const int n_seg = in_sizes[1];            // 2048
    const int D     = out_size / n_seg;       // 128
    const int nc4   = D >> 2;                 // 32

    // ws layout: [starts: n_seg ints][pad to 16 KB][partials: n_seg*SLICES*D floats]
    int*   starts   = (int*)d_ws;
    float* partials = (float*)((char*)d_ws + 16384);

    scan_kernel<<<1, BLOCK, 0, stream>>>(sizes, starts, n_seg);
    seg_max_kernel<<<n_seg * SLICES, BLOCK, 0, stream>>>(x, sizes, starts, wptr,
                                                         partials, nc4);
    const int total4 = n_seg * nc4;
    combine_kernel<<<(total4 + BLOCK - 1) / BLOCK, BLOCK, 0, stream>>>(
        partials, out, total4, nc4);
}